// Round 8
// baseline (163.974 us; speedup 1.0000x reference)
//
#include <hip/hip_runtime.h>
#include <math.h>

#define HW_   128
#define CIN_  64
#define IMG_  (HW_ * HW_)       // 16384

// 2 output rows x 32 output cols per block
#define TR_    6                // tile rows  [h0-2 .. h0+3]
#define TC_    40               // tile cols  [w0-4 .. w0+35]
#define PIT_   32               // dwords per pixel (64ch bf16, no pad)
                                // bank conflicts handled by chunk-XOR swizzle
#define TILEDW (TR_ * TC_ * PIT_)   // 7680 dw = 30720 B -> 5 blocks/CU
#define NU_    (TR_ * 8 * 10)       // 480 staging units (r, cq, cc)

typedef short    s16x8 __attribute__((ext_vector_type(8)));
typedef float    f32x4 __attribute__((ext_vector_type(4)));
typedef float    f32x2 __attribute__((ext_vector_type(2)));
typedef unsigned u32x4 __attribute__((ext_vector_type(4)));

__device__ __forceinline__ short f2bf(float f) {
  union { float f; unsigned i; } v; v.f = f;
  unsigned r = (v.i + 0x7fffu + ((v.i >> 16) & 1u)) >> 16;   // RNE
  return (short)r;
}

#if defined(__has_builtin)
#if __has_builtin(__builtin_amdgcn_cvt_pk_bf16_f32)
#define HAVE_CVT_PK_BF16 1
#endif
#endif

// pack two f32 -> bf16 pair (lo=a, hi=b)
__device__ __forceinline__ unsigned PK2(float a, float b) {
#ifdef HAVE_CVT_PK_BF16
  typedef __bf16 bf16x2_t __attribute__((ext_vector_type(2)));
  union { bf16x2_t v; unsigned u; } cv;
  cv.v = __builtin_amdgcn_cvt_pk_bf16_f32(a, b);
  return cv.u;
#else
  union { float f; unsigned u; } ua, ub; ua.f = a; ub.f = b;
  unsigned ra = ua.u + 0x7fffu + ((ua.u >> 16) & 1u);
  unsigned rb = ub.u + 0x7fffu + ((ub.u >> 16) & 1u);
  return __builtin_amdgcn_perm(rb, ra, 0x07060302u);
#endif
}

// dirty-hi f32x2 unpack of a bf16 pair: elem0 exact (d<<16), elem1 keeps the
// junk low 16 mantissa bits (rel err ~2^-16, far below the 2^-9 bf16 repack
// rounding). 1 VALU op per dword; blend chains on f32x2 emit v_pk_fma_f32.
__device__ __forceinline__ f32x2 up2d(unsigned d) {
  union { unsigned u; float f; } lo, hi;
  lo.u = d << 16; hi.u = d;
  return (f32x2){lo.f, hi.f};
}

// ws layout (bytes):
//   [0,     36864)  wOf bf16 [j:9][ks:2][q:4][m:32][i:8]  (A-frag order, m>=27 zero)
//   [36864, 110592) wA  bf16 [j:9][ks:2][q:4][o:64][i:8]  (A-frag order)

__global__ __launch_bounds__(256) void wprep(const float* __restrict__ w_off,
                                             const float* __restrict__ w_conv,
                                             short* __restrict__ wOf,
                                             short* __restrict__ wA) {
  int t = blockIdx.x * 256 + threadIdx.x;
  if (t < 36864) {
    int i = t & 7, o = (t >> 3) & 63, q = (t >> 9) & 3, ks = (t >> 11) & 1, j = t >> 12;
    int c = ks * 32 + q * 8 + i;
    wA[t] = f2bf(w_conv[o * 576 + c * 9 + j]);
  }
  if (t < 18432) {
    int i = t & 7, m = (t >> 3) & 31, q = (t >> 8) & 3, ks = (t >> 10) & 1, j = t >> 11;
    int c = ks * 32 + q * 8 + i;
    wOf[t] = (m < 27) ? f2bf(w_off[(m * 64 + c) * 9 + j]) : (short)0;
  }
}

// Fully fused: stage f32 NCHW -> bf16 NHWC halo tile in SWIZZLED LDS
// (zero-filled OOB, one barrier), offset conv (MFMA), shuffle-exchange
// offsets, LDS-gather sampling + MFMA GEMM (f32 global fallback for |o|>=1).
// Round-8 = round-7 staging (direct from x, T14 batched, channel-quad b128
// writes) + round-5 LDS geometry (PIT 32 + chunk-XOR swizzle -> 30720 B,
// 5 blocks/CU, measured 2.3M conflicts vs 4.4M at PIT 36).
// Swizzle: chunk' = chunk ^ (c & 7), c = tile col. ks1 chunk = addr ^ 16 dw.
__global__ __launch_bounds__(256)
__attribute__((amdgpu_waves_per_eu(5)))
void dfuse(const float* __restrict__ x,
           const short* __restrict__ wOf,
           const float* __restrict__ b_off,
           const short* __restrict__ wA,
           float* __restrict__ out) {
  __shared__ __align__(16) unsigned lds_[TILEDW];

  int bi  = blockIdx.x & 7;        // XCD-aligned image index
  int tid = blockIdx.x >> 3;       // 0..255 tile within image
  int h0  = (tid >> 2) << 1;       // 0,2,..,126
  int w0  = (tid & 3) << 5;        // 0,32,64,96
  int t   = threadIdx.x;
  int wv  = t >> 6, l = t & 63;
  int col = l & 15, q = l >> 4;
  int px_local = wv * 16 + col;    // 0..63
  int rl  = px_local >> 5;         // local row 0..1
  int cl  = px_local & 31;         // local col 0..31
  int h   = h0 + rl;
  int w   = w0 + cl;
  int p   = h * HW_ + w;

  const float* xB = x + (size_t)bi * (CIN_ * IMG_);

  // ---- stage halo tile: rows h0-2..h0+3, cols w0-4..w0+35, 64 ch bf16 ----
  // unit u: cc = u%10 (4-px chunk), cq = (u/10)%8 (channels 8cq..8cq+7),
  // r = u/80. Unit A = t, unit B = t+256 (first 224 threads only).
  // Write: one ds_write_b128 per pixel at swizzled chunk (cq ^ (c&7)).
  {
    f32x4 L0a[4], L1a[4], L0b[4], L1b[4];
    int baseA, baseB, swA, swB;
    unsigned ma, mb;
    {
      int u = t;
      int cc = u % 10, cq = (u / 10) & 7, r = u / 80;
      int y  = h0 - 2 + r;
      int ys = min(max(y, 0), HW_ - 1);
      int xg0 = w0 - 4 + cc * 4;
      int xs  = min(max(xg0, 0), HW_ - 4);             // 16B-aligned
      ma = ((y >= 0) && (y < HW_) && (xg0 >= 0) && (xg0 < HW_)) ? 0xffffffffu : 0u;
      const float* s0 = xB + (size_t)(8 * cq) * IMG_ + ys * HW_ + xs;
#pragma unroll
      for (int i = 0; i < 4; ++i) {
        L0a[i] = *(const f32x4*)(s0 + (2 * i) * IMG_);
        L1a[i] = *(const f32x4*)(s0 + (2 * i + 1) * IMG_);
      }
      baseA = (r * TC_ + cc * 4) * PIT_;
      swA   = cq ^ ((cc & 1) << 2);          // ^ pxi applied per store
    }
    bool hasB = (t + 256) < NU_;
    {
      int u = hasB ? (t + 256) : 0;
      int cc = u % 10, cq = (u / 10) & 7, r = u / 80;
      int y  = h0 - 2 + r;
      int ys = min(max(y, 0), HW_ - 1);
      int xg0 = w0 - 4 + cc * 4;
      int xs  = min(max(xg0, 0), HW_ - 4);
      mb = ((y >= 0) && (y < HW_) && (xg0 >= 0) && (xg0 < HW_)) ? 0xffffffffu : 0u;
      const float* s0 = xB + (size_t)(8 * cq) * IMG_ + ys * HW_ + xs;
#pragma unroll
      for (int i = 0; i < 4; ++i) {
        L0b[i] = *(const f32x4*)(s0 + (2 * i) * IMG_);
        L1b[i] = *(const f32x4*)(s0 + (2 * i + 1) * IMG_);
      }
      baseB = (r * TC_ + cc * 4) * PIT_;
      swB   = cq ^ ((cc & 1) << 2);
    }
#pragma unroll
    for (int pxi = 0; pxi < 4; ++pxi) {
      u32x4 v;
#pragma unroll
      for (int i = 0; i < 4; ++i) v[i] = PK2(L0a[i][pxi], L1a[i][pxi]) & ma;
      *(u32x4*)(lds_ + baseA + pxi * PIT_ + ((swA ^ pxi) << 2)) = v;
    }
    if (hasB) {
#pragma unroll
      for (int pxi = 0; pxi < 4; ++pxi) {
        u32x4 v;
#pragma unroll
        for (int i = 0; i < 4; ++i) v[i] = PK2(L0b[i][pxi], L1b[i][pxi]) & mb;
        *(u32x4*)(lds_ + baseB + pxi * PIT_ + ((swB ^ pxi) << 2)) = v;
      }
    }
  }
  __syncthreads();

  // ---- phase 1: offset conv from tile (tile is zero-padded: no masking) ----
  float oall[32];
  {
    const short* wq_ = wOf + q * 256 + col * 8;
    f32x4 a0v = {0.f, 0.f, 0.f, 0.f};
    f32x4 a1v = {0.f, 0.f, 0.f, 0.f};
    f32x4 a0w = {0.f, 0.f, 0.f, 0.f};
    f32x4 a1w = {0.f, 0.f, 0.f, 0.f};
    const unsigned* tbp = lds_ + ((rl + 2) * TC_ + (cl + 4)) * PIT_;
#pragma unroll
    for (int j = 0; j < 9; ++j) {
      int dy = j / 3 - 1, dx = j % 3 - 1;
      int ca = (q ^ ((cl + 4 + dx) & 7)) << 2;
      const unsigned* pb = tbp + (dy * TC_ + dx) * PIT_;
      union { u32x4 u; s16x8 v; } B0, B1;
      B0.u = *(const u32x4*)(pb + ca);
      B1.u = *(const u32x4*)(pb + (ca ^ 16));
      const short* wj = wq_ + j * 2048;
      s16x8 a00 = *(const s16x8*)(wj);
      s16x8 a01 = *(const s16x8*)(wj + 128);
      s16x8 a10 = *(const s16x8*)(wj + 1024);
      s16x8 a11 = *(const s16x8*)(wj + 1024 + 128);
      a0v = __builtin_amdgcn_mfma_f32_16x16x32_bf16(a00, B0.v, a0v, 0, 0, 0);
      a1v = __builtin_amdgcn_mfma_f32_16x16x32_bf16(a01, B0.v, a1v, 0, 0, 0);
      a0w = __builtin_amdgcn_mfma_f32_16x16x32_bf16(a10, B1.v, a0w, 0, 0, 0);
      a1w = __builtin_amdgcn_mfma_f32_16x16x32_bf16(a11, B1.v, a1w, 0, 0, 0);
    }
    a0v += a0w;
    a1v += a1w;
    // bias + sigmoid by producer lanes, then wave-local shuffle exchange
    float myv[8];
#pragma unroll
    for (int r = 0; r < 4; ++r) myv[r] = a0v[r] + b_off[q * 4 + r];
#pragma unroll
    for (int r = 0; r < 4; ++r) {
      int ch = 16 + q * 4 + r;
      float bo = b_off[min(ch, 26)];
      float v = a1v[r] + bo;
      myv[4 + r] = (ch >= 18) ? (1.f / (1.f + __expf(-v))) : v;
    }
#pragma unroll
    for (int qq = 0; qq < 4; ++qq) {
      int src = qq * 16 + col;
#pragma unroll
      for (int r = 0; r < 4; ++r) {
        oall[qq * 4 + r]      = __shfl(myv[r], src);
        oall[16 + qq * 4 + r] = __shfl(myv[4 + r], src);
      }
    }
  }

  // ---- phase 3: LDS-gather sampling + MFMA GEMM ----
  f32x4 acc[4], accB[4];
#pragma unroll
  for (int ms = 0; ms < 4; ++ms) {
    acc[ms]  = (f32x4){0.f, 0.f, 0.f, 0.f};
    accB[ms] = (f32x4){0.f, 0.f, 0.f, 0.f};
  }

  const short* wqA = wA + q * 512 + col * 8;

#pragma unroll
  for (int j = 0; j < 9; ++j) {
    float o1 = oall[j], o2 = oall[9 + j], mk = oall[18 + j];

    float pxf = o1 + (float)(w + (j % 3) - 1);
    float pyf = o2 + (float)(h + (j / 3) - 1);
    float fx = floorf(pxf), fy = floorf(pyf);
    int   x0 = (int)fx,   y0 = (int)fy;
    float ax = pxf - fx, ay = pyf - fy;
    float bx = 1.f - ax, by = 1.f - ay;

    // validity factorizes per-axis: zero the axis weight instead of the product
    bx = (x0 >= 0  && x0 < HW_)     ? bx : 0.f;
    ax = (x0 >= -1 && x0 < HW_ - 1) ? ax : 0.f;
    by = (y0 >= 0  && y0 < HW_)     ? by : 0.f;
    ay = (y0 >= -1 && y0 < HW_ - 1) ? ay : 0.f;
    float bym = by * mk, aym = ay * mk;
    float u00 = bym * bx, u01 = bym * ax;
    float u10 = aym * bx, u11 = aym * ax;
    f32x2 U00 = {u00, u00}, U01 = {u01, u01};
    f32x2 U10 = {u10, u10}, U11 = {u11, u11};

    u32x4 A00, A01, A10, A11, B00, B01, B10, B11;
    bool intile = (o1 >= -1.f) && (o1 < 1.f) && (o2 >= -1.f) && (o2 < 1.f);
    if (intile) {
      // r0 in [0,4], c0 in [2,36] -> no clamps; swizzled chunk addressing.
      int r0 = y0 - (h0 - 2), c0 = x0 - (w0 - 4);
      const unsigned* b00 = lds_ + (r0 * TC_ + c0) * PIT_;
      int s0 = (q ^ (c0 & 7)) << 2;
      int s1 = (q ^ ((c0 + 1) & 7)) << 2;
      A00 = *(const u32x4*)(b00 + s0);
      A01 = *(const u32x4*)(b00 + PIT_ + s1);
      A10 = *(const u32x4*)(b00 + TC_ * PIT_ + s0);
      A11 = *(const u32x4*)(b00 + TC_ * PIT_ + PIT_ + s1);
      B00 = *(const u32x4*)(b00 + (s0 ^ 16));
      B01 = *(const u32x4*)(b00 + PIT_ + (s1 ^ 16));
      B10 = *(const u32x4*)(b00 + TC_ * PIT_ + (s0 ^ 16));
      B11 = *(const u32x4*)(b00 + TC_ * PIT_ + PIT_ + (s1 ^ 16));
    } else {
      // rare fallback: gather straight from f32 NCHW x (clamps only here)
      int xc0 = min(max(x0, 0), HW_ - 1), xc1 = min(max(x0 + 1, 0), HW_ - 1);
      int yc0 = min(max(y0, 0), HW_ - 1), yc1 = min(max(y0 + 1, 0), HW_ - 1);
      int g00 = yc0 * HW_ + xc0, g01 = yc0 * HW_ + xc1;
      int g10 = yc1 * HW_ + xc0, g11 = yc1 * HW_ + xc1;
#pragma unroll
      for (int hB = 0; hB < 2; ++hB) {
#pragma unroll
        for (int ii = 0; ii < 4; ++ii) {
          int c0i = hB * 32 + q * 8 + 2 * ii;
          const float* pc = xB + c0i * IMG_;
          const float* pd = pc + IMG_;
          unsigned v00 = PK2(pc[g00], pd[g00]);
          unsigned v01 = PK2(pc[g01], pd[g01]);
          unsigned v10 = PK2(pc[g10], pd[g10]);
          unsigned v11 = PK2(pc[g11], pd[g11]);
          if (hB) { B00[ii] = v00; B01[ii] = v01; B10[ii] = v10; B11[ii] = v11; }
          else    { A00[ii] = v00; A01[ii] = v01; A10[ii] = v10; A11[ii] = v11; }
        }
      }
    }

    unsigned F0u[4], F1u[4];
#pragma unroll
    for (int i = 0; i < 4; ++i) {
      f32x2 v0 = up2d(A00[i]) * U00 + up2d(A01[i]) * U01
               + up2d(A10[i]) * U10 + up2d(A11[i]) * U11;   // v_pk_fma_f32
      F0u[i] = PK2(v0.x, v0.y);
      f32x2 v1 = up2d(B00[i]) * U00 + up2d(B01[i]) * U01
               + up2d(B10[i]) * U10 + up2d(B11[i]) * U11;
      F1u[i] = PK2(v1.x, v1.y);
    }

    union { unsigned u[4]; s16x8 v; } F0, F1;
#pragma unroll
    for (int i = 0; i < 4; ++i) { F0.u[i] = F0u[i]; F1.u[i] = F1u[i]; }

    const short* wj = wqA + j * 4096;
#pragma unroll
    for (int ms = 0; ms < 4; ++ms) {
      s16x8 a0 = *(const s16x8*)(wj + ms * 128);
      acc[ms] = __builtin_amdgcn_mfma_f32_16x16x32_bf16(a0, F0.v, acc[ms], 0, 0, 0);
    }
#pragma unroll
    for (int ms = 0; ms < 4; ++ms) {
      s16x8 a1 = *(const s16x8*)(wj + 2048 + ms * 128);
      accB[ms] = __builtin_amdgcn_mfma_f32_16x16x32_bf16(a1, F1.v, accB[ms], 0, 0, 0);
    }
  }

  float* op = out + (size_t)bi * (CIN_ * IMG_) + p;
#pragma unroll
  for (int ms = 0; ms < 4; ++ms) {
    f32x4 r = acc[ms] + accB[ms];
#pragma unroll
    for (int rr = 0; rr < 4; ++rr)
      op[(ms * 16 + q * 4 + rr) * IMG_] = r[rr];
  }
}

extern "C" void kernel_launch(void* const* d_in, const int* in_sizes, int n_in,
                              void* d_out, int out_size, void* d_ws, size_t ws_size,
                              hipStream_t stream) {
  const float* x      = (const float*)d_in[0];
  const float* w_off  = (const float*)d_in[1];
  const float* b_off  = (const float*)d_in[2];
  const float* w_conv = (const float*)d_in[3];
  float* out = (float*)d_out;

  char* ws = (char*)d_ws;
  short* wOf = (short*)(ws);
  short* wA  = (short*)(ws + 36864);

  hipLaunchKernelGGL(wprep, dim3(144),  dim3(256), 0, stream, w_off, w_conv, wOf, wA);
  hipLaunchKernelGGL(dfuse, dim3(2048), dim3(256), 0, stream, x, wOf, b_off, wA, out);
}

// Round 9
// 146.305 us; speedup vs baseline: 1.1208x; 1.1208x over previous
//
#include <hip/hip_runtime.h>
#include <math.h>

#define HW_   128
#define CIN_  64
#define IMG_  (HW_ * HW_)       // 16384

// 2 output rows x 32 output cols per block
#define TR_    6                // tile rows  [h0-2 .. h0+3]
#define TC_    40               // tile cols  [w0-4 .. w0+35]
#define PIT_   32               // dwords per pixel (64ch bf16, no pad)
                                // bank conflicts handled by chunk-XOR swizzle
#define TILEDW (TR_ * TC_ * PIT_)   // 7680 dw = 30720 B -> 5 blocks/CU (LDS-limited)
#define NU_    (TR_ * 8 * 10)       // 480 staging units (r, cq, cc)

typedef short    s16x8 __attribute__((ext_vector_type(8)));
typedef float    f32x4 __attribute__((ext_vector_type(4)));
typedef float    f32x2 __attribute__((ext_vector_type(2)));
typedef unsigned u32x4 __attribute__((ext_vector_type(4)));

__device__ __forceinline__ short f2bf(float f) {
  union { float f; unsigned i; } v; v.f = f;
  unsigned r = (v.i + 0x7fffu + ((v.i >> 16) & 1u)) >> 16;   // RNE
  return (short)r;
}

#if defined(__has_builtin)
#if __has_builtin(__builtin_amdgcn_cvt_pk_bf16_f32)
#define HAVE_CVT_PK_BF16 1
#endif
#endif

// pack two f32 -> bf16 pair (lo=a, hi=b)
__device__ __forceinline__ unsigned PK2(float a, float b) {
#ifdef HAVE_CVT_PK_BF16
  typedef __bf16 bf16x2_t __attribute__((ext_vector_type(2)));
  union { bf16x2_t v; unsigned u; } cv;
  cv.v = __builtin_amdgcn_cvt_pk_bf16_f32(a, b);
  return cv.u;
#else
  union { float f; unsigned u; } ua, ub; ua.f = a; ub.f = b;
  unsigned ra = ua.u + 0x7fffu + ((ua.u >> 16) & 1u);
  unsigned rb = ub.u + 0x7fffu + ((ub.u >> 16) & 1u);
  return __builtin_amdgcn_perm(rb, ra, 0x07060302u);
#endif
}

// dirty-hi f32x2 unpack of a bf16 pair: elem0 exact (d<<16), elem1 keeps the
// junk low 16 mantissa bits (rel err ~2^-16, far below the 2^-9 bf16 repack
// rounding). 1 VALU op per dword; blend chains on f32x2 emit v_pk_fma_f32.
__device__ __forceinline__ f32x2 up2d(unsigned d) {
  union { unsigned u; float f; } lo, hi;
  lo.u = d << 16; hi.u = d;
  return (f32x2){lo.f, hi.f};
}

// ws layout (bytes):
//   [0,     36864)  wOf bf16 [j:9][ks:2][q:4][m:32][i:8]  (A-frag order, m>=27 zero)
//   [36864, 110592) wA  bf16 [j:9][ks:2][q:4][o:64][i:8]  (A-frag order)

__global__ __launch_bounds__(256) void wprep(const float* __restrict__ w_off,
                                             const float* __restrict__ w_conv,
                                             short* __restrict__ wOf,
                                             short* __restrict__ wA) {
  int t = blockIdx.x * 256 + threadIdx.x;
  if (t < 36864) {
    int i = t & 7, o = (t >> 3) & 63, q = (t >> 9) & 3, ks = (t >> 11) & 1, j = t >> 12;
    int c = ks * 32 + q * 8 + i;
    wA[t] = f2bf(w_conv[o * 576 + c * 9 + j]);
  }
  if (t < 18432) {
    int i = t & 7, m = (t >> 3) & 31, q = (t >> 8) & 3, ks = (t >> 10) & 1, j = t >> 11;
    int c = ks * 32 + q * 8 + i;
    wOf[t] = (m < 27) ? f2bf(w_off[(m * 64 + c) * 9 + j]) : (short)0;
  }
}

// Fully fused: stage f32 NCHW -> bf16 NHWC halo tile in SWIZZLED LDS
// (zero-filled OOB, one barrier), offset conv (MFMA), shuffle-exchange
// offsets, LDS-gather sampling + MFMA GEMM (f32 global fallback for |o|>=1).
// Round-9 = round-8 geometry with waves_per_eu(4) NOT (5): wpe(5) capped
// VGPRs at 48 -> the 64-VGPR T14 staging batch spilled to scratch (HBM!),
// seen as WRITE_SIZE 33->85MB, FETCH 17->44MB, dur 57->95us. wpe(4) compiles
// this staging at 64 VGPR (r6/r7 evidence) with zero spill; occupancy is
// then LDS-limited at 5 blocks/CU (20 waves/CU) -- the gain wpe(5) chased,
// without the spill.
__global__ __launch_bounds__(256)
__attribute__((amdgpu_waves_per_eu(4)))
void dfuse(const float* __restrict__ x,
           const short* __restrict__ wOf,
           const float* __restrict__ b_off,
           const short* __restrict__ wA,
           float* __restrict__ out) {
  __shared__ __align__(16) unsigned lds_[TILEDW];

  int bi  = blockIdx.x & 7;        // XCD-aligned image index
  int tid = blockIdx.x >> 3;       // 0..255 tile within image
  int h0  = (tid >> 2) << 1;       // 0,2,..,126
  int w0  = (tid & 3) << 5;        // 0,32,64,96
  int t   = threadIdx.x;
  int wv  = t >> 6, l = t & 63;
  int col = l & 15, q = l >> 4;
  int px_local = wv * 16 + col;    // 0..63
  int rl  = px_local >> 5;         // local row 0..1
  int cl  = px_local & 31;         // local col 0..31
  int h   = h0 + rl;
  int w   = w0 + cl;
  int p   = h * HW_ + w;

  const float* xB = x + (size_t)bi * (CIN_ * IMG_);

  // ---- stage halo tile: rows h0-2..h0+3, cols w0-4..w0+35, 64 ch bf16 ----
  // unit u: cc = u%10 (4-px chunk), cq = (u/10)%8 (channels 8cq..8cq+7),
  // r = u/80. Unit A = t, unit B = t+256 (first 224 threads only).
  // Write: one ds_write_b128 per pixel at swizzled chunk (cq ^ (c&7)).
  {
    f32x4 L0a[4], L1a[4], L0b[4], L1b[4];
    int baseA, baseB, swA, swB;
    unsigned ma, mb;
    {
      int u = t;
      int cc = u % 10, cq = (u / 10) & 7, r = u / 80;
      int y  = h0 - 2 + r;
      int ys = min(max(y, 0), HW_ - 1);
      int xg0 = w0 - 4 + cc * 4;
      int xs  = min(max(xg0, 0), HW_ - 4);             // 16B-aligned
      ma = ((y >= 0) && (y < HW_) && (xg0 >= 0) && (xg0 < HW_)) ? 0xffffffffu : 0u;
      const float* s0 = xB + (size_t)(8 * cq) * IMG_ + ys * HW_ + xs;
#pragma unroll
      for (int i = 0; i < 4; ++i) {
        L0a[i] = *(const f32x4*)(s0 + (2 * i) * IMG_);
        L1a[i] = *(const f32x4*)(s0 + (2 * i + 1) * IMG_);
      }
      baseA = (r * TC_ + cc * 4) * PIT_;
      swA   = cq ^ ((cc & 1) << 2);          // ^ pxi applied per store
    }
    bool hasB = (t + 256) < NU_;
    {
      int u = hasB ? (t + 256) : 0;
      int cc = u % 10, cq = (u / 10) & 7, r = u / 80;
      int y  = h0 - 2 + r;
      int ys = min(max(y, 0), HW_ - 1);
      int xg0 = w0 - 4 + cc * 4;
      int xs  = min(max(xg0, 0), HW_ - 4);
      mb = ((y >= 0) && (y < HW_) && (xg0 >= 0) && (xg0 < HW_)) ? 0xffffffffu : 0u;
      const float* s0 = xB + (size_t)(8 * cq) * IMG_ + ys * HW_ + xs;
#pragma unroll
      for (int i = 0; i < 4; ++i) {
        L0b[i] = *(const f32x4*)(s0 + (2 * i) * IMG_);
        L1b[i] = *(const f32x4*)(s0 + (2 * i + 1) * IMG_);
      }
      baseB = (r * TC_ + cc * 4) * PIT_;
      swB   = cq ^ ((cc & 1) << 2);
    }
#pragma unroll
    for (int pxi = 0; pxi < 4; ++pxi) {
      u32x4 v;
#pragma unroll
      for (int i = 0; i < 4; ++i) v[i] = PK2(L0a[i][pxi], L1a[i][pxi]) & ma;
      *(u32x4*)(lds_ + baseA + pxi * PIT_ + ((swA ^ pxi) << 2)) = v;
    }
    if (hasB) {
#pragma unroll
      for (int pxi = 0; pxi < 4; ++pxi) {
        u32x4 v;
#pragma unroll
        for (int i = 0; i < 4; ++i) v[i] = PK2(L0b[i][pxi], L1b[i][pxi]) & mb;
        *(u32x4*)(lds_ + baseB + pxi * PIT_ + ((swB ^ pxi) << 2)) = v;
      }
    }
  }
  __syncthreads();

  // ---- phase 1: offset conv from tile (tile is zero-padded: no masking) ----
  float oall[32];
  {
    const short* wq_ = wOf + q * 256 + col * 8;
    f32x4 a0v = {0.f, 0.f, 0.f, 0.f};
    f32x4 a1v = {0.f, 0.f, 0.f, 0.f};
    f32x4 a0w = {0.f, 0.f, 0.f, 0.f};
    f32x4 a1w = {0.f, 0.f, 0.f, 0.f};
    const unsigned* tbp = lds_ + ((rl + 2) * TC_ + (cl + 4)) * PIT_;
#pragma unroll
    for (int j = 0; j < 9; ++j) {
      int dy = j / 3 - 1, dx = j % 3 - 1;
      int ca = (q ^ ((cl + 4 + dx) & 7)) << 2;
      const unsigned* pb = tbp + (dy * TC_ + dx) * PIT_;
      union { u32x4 u; s16x8 v; } B0, B1;
      B0.u = *(const u32x4*)(pb + ca);
      B1.u = *(const u32x4*)(pb + (ca ^ 16));
      const short* wj = wq_ + j * 2048;
      s16x8 a00 = *(const s16x8*)(wj);
      s16x8 a01 = *(const s16x8*)(wj + 128);
      s16x8 a10 = *(const s16x8*)(wj + 1024);
      s16x8 a11 = *(const s16x8*)(wj + 1024 + 128);
      a0v = __builtin_amdgcn_mfma_f32_16x16x32_bf16(a00, B0.v, a0v, 0, 0, 0);
      a1v = __builtin_amdgcn_mfma_f32_16x16x32_bf16(a01, B0.v, a1v, 0, 0, 0);
      a0w = __builtin_amdgcn_mfma_f32_16x16x32_bf16(a10, B1.v, a0w, 0, 0, 0);
      a1w = __builtin_amdgcn_mfma_f32_16x16x32_bf16(a11, B1.v, a1w, 0, 0, 0);
    }
    a0v += a0w;
    a1v += a1w;
    // bias + sigmoid by producer lanes, then wave-local shuffle exchange
    float myv[8];
#pragma unroll
    for (int r = 0; r < 4; ++r) myv[r] = a0v[r] + b_off[q * 4 + r];
#pragma unroll
    for (int r = 0; r < 4; ++r) {
      int ch = 16 + q * 4 + r;
      float bo = b_off[min(ch, 26)];
      float v = a1v[r] + bo;
      myv[4 + r] = (ch >= 18) ? (1.f / (1.f + __expf(-v))) : v;
    }
#pragma unroll
    for (int qq = 0; qq < 4; ++qq) {
      int src = qq * 16 + col;
#pragma unroll
      for (int r = 0; r < 4; ++r) {
        oall[qq * 4 + r]      = __shfl(myv[r], src);
        oall[16 + qq * 4 + r] = __shfl(myv[4 + r], src);
      }
    }
  }

  // ---- phase 3: LDS-gather sampling + MFMA GEMM ----
  f32x4 acc[4], accB[4];
#pragma unroll
  for (int ms = 0; ms < 4; ++ms) {
    acc[ms]  = (f32x4){0.f, 0.f, 0.f, 0.f};
    accB[ms] = (f32x4){0.f, 0.f, 0.f, 0.f};
  }

  const short* wqA = wA + q * 512 + col * 8;

#pragma unroll
  for (int j = 0; j < 9; ++j) {
    float o1 = oall[j], o2 = oall[9 + j], mk = oall[18 + j];

    float pxf = o1 + (float)(w + (j % 3) - 1);
    float pyf = o2 + (float)(h + (j / 3) - 1);
    float fx = floorf(pxf), fy = floorf(pyf);
    int   x0 = (int)fx,   y0 = (int)fy;
    float ax = pxf - fx, ay = pyf - fy;
    float bx = 1.f - ax, by = 1.f - ay;

    // validity factorizes per-axis: zero the axis weight instead of the product
    bx = (x0 >= 0  && x0 < HW_)     ? bx : 0.f;
    ax = (x0 >= -1 && x0 < HW_ - 1) ? ax : 0.f;
    by = (y0 >= 0  && y0 < HW_)     ? by : 0.f;
    ay = (y0 >= -1 && y0 < HW_ - 1) ? ay : 0.f;
    float bym = by * mk, aym = ay * mk;
    float u00 = bym * bx, u01 = bym * ax;
    float u10 = aym * bx, u11 = aym * ax;
    f32x2 U00 = {u00, u00}, U01 = {u01, u01};
    f32x2 U10 = {u10, u10}, U11 = {u11, u11};

    u32x4 A00, A01, A10, A11, B00, B01, B10, B11;
    bool intile = (o1 >= -1.f) && (o1 < 1.f) && (o2 >= -1.f) && (o2 < 1.f);
    if (intile) {
      // r0 in [0,4], c0 in [2,36] -> no clamps; swizzled chunk addressing.
      int r0 = y0 - (h0 - 2), c0 = x0 - (w0 - 4);
      const unsigned* b00 = lds_ + (r0 * TC_ + c0) * PIT_;
      int s0 = (q ^ (c0 & 7)) << 2;
      int s1 = (q ^ ((c0 + 1) & 7)) << 2;
      A00 = *(const u32x4*)(b00 + s0);
      A01 = *(const u32x4*)(b00 + PIT_ + s1);
      A10 = *(const u32x4*)(b00 + TC_ * PIT_ + s0);
      A11 = *(const u32x4*)(b00 + TC_ * PIT_ + PIT_ + s1);
      B00 = *(const u32x4*)(b00 + (s0 ^ 16));
      B01 = *(const u32x4*)(b00 + PIT_ + (s1 ^ 16));
      B10 = *(const u32x4*)(b00 + TC_ * PIT_ + (s0 ^ 16));
      B11 = *(const u32x4*)(b00 + TC_ * PIT_ + PIT_ + (s1 ^ 16));
    } else {
      // rare fallback: gather straight from f32 NCHW x (clamps only here)
      int xc0 = min(max(x0, 0), HW_ - 1), xc1 = min(max(x0 + 1, 0), HW_ - 1);
      int yc0 = min(max(y0, 0), HW_ - 1), yc1 = min(max(y0 + 1, 0), HW_ - 1);
      int g00 = yc0 * HW_ + xc0, g01 = yc0 * HW_ + xc1;
      int g10 = yc1 * HW_ + xc0, g11 = yc1 * HW_ + xc1;
#pragma unroll
      for (int hB = 0; hB < 2; ++hB) {
#pragma unroll
        for (int ii = 0; ii < 4; ++ii) {
          int c0i = hB * 32 + q * 8 + 2 * ii;
          const float* pc = xB + c0i * IMG_;
          const float* pd = pc + IMG_;
          unsigned v00 = PK2(pc[g00], pd[g00]);
          unsigned v01 = PK2(pc[g01], pd[g01]);
          unsigned v10 = PK2(pc[g10], pd[g10]);
          unsigned v11 = PK2(pc[g11], pd[g11]);
          if (hB) { B00[ii] = v00; B01[ii] = v01; B10[ii] = v10; B11[ii] = v11; }
          else    { A00[ii] = v00; A01[ii] = v01; A10[ii] = v10; A11[ii] = v11; }
        }
      }
    }

    unsigned F0u[4], F1u[4];
#pragma unroll
    for (int i = 0; i < 4; ++i) {
      f32x2 v0 = up2d(A00[i]) * U00 + up2d(A01[i]) * U01
               + up2d(A10[i]) * U10 + up2d(A11[i]) * U11;   // v_pk_fma_f32
      F0u[i] = PK2(v0.x, v0.y);
      f32x2 v1 = up2d(B00[i]) * U00 + up2d(B01[i]) * U01
               + up2d(B10[i]) * U10 + up2d(B11[i]) * U11;
      F1u[i] = PK2(v1.x, v1.y);
    }

    union { unsigned u[4]; s16x8 v; } F0, F1;
#pragma unroll
    for (int i = 0; i < 4; ++i) { F0.u[i] = F0u[i]; F1.u[i] = F1u[i]; }

    const short* wj = wqA + j * 4096;
#pragma unroll
    for (int ms = 0; ms < 4; ++ms) {
      s16x8 a0 = *(const s16x8*)(wj + ms * 128);
      acc[ms] = __builtin_amdgcn_mfma_f32_16x16x32_bf16(a0, F0.v, acc[ms], 0, 0, 0);
    }
#pragma unroll
    for (int ms = 0; ms < 4; ++ms) {
      s16x8 a1 = *(const s16x8*)(wj + 2048 + ms * 128);
      accB[ms] = __builtin_amdgcn_mfma_f32_16x16x32_bf16(a1, F1.v, accB[ms], 0, 0, 0);
    }
  }

  float* op = out + (size_t)bi * (CIN_ * IMG_) + p;
#pragma unroll
  for (int ms = 0; ms < 4; ++ms) {
    f32x4 r = acc[ms] + accB[ms];
#pragma unroll
    for (int rr = 0; rr < 4; ++rr)
      op[(ms * 16 + q * 4 + rr) * IMG_] = r[rr];
  }
}

extern "C" void kernel_launch(void* const* d_in, const int* in_sizes, int n_in,
                              void* d_out, int out_size, void* d_ws, size_t ws_size,
                              hipStream_t stream) {
  const float* x      = (const float*)d_in[0];
  const float* w_off  = (const float*)d_in[1];
  const float* b_off  = (const float*)d_in[2];
  const float* w_conv = (const float*)d_in[3];
  float* out = (float*)d_out;

  char* ws = (char*)d_ws;
  short* wOf = (short*)(ws);
  short* wA  = (short*)(ws + 36864);

  hipLaunchKernelGGL(wprep, dim3(144),  dim3(256), 0, stream, w_off, w_conv, wOf, wA);
  hipLaunchKernelGGL(dfuse, dim3(2048), dim3(256), 0, stream, x, wOf, b_off, wA, out);
}

// Round 10
// 129.410 us; speedup vs baseline: 1.2671x; 1.1306x over previous
//
#include <hip/hip_runtime.h>
#include <math.h>

#define HW_   128
#define CIN_  64
#define IMG_  (HW_ * HW_)       // 16384

// 2 output rows x 32 output cols per block
#define TR_    6                // tile rows  [h0-2 .. h0+3]
#define TC_    40               // tile cols  [w0-4 .. w0+35]
#define PIT_   32               // dwords per pixel (64ch bf16, no pad)
                                // bank conflicts handled by chunk-XOR swizzle
#define TILEDW (TR_ * TC_ * PIT_)   // 7680 dw = 30720 B -> 5 blocks/CU (LDS-limited)
#define NU_    (TR_ * 8 * 10)       // 480 staging units (r, cq, cc)

typedef short    s16x8 __attribute__((ext_vector_type(8)));
typedef float    f32x4 __attribute__((ext_vector_type(4)));
typedef float    f32x2 __attribute__((ext_vector_type(2)));
typedef unsigned u32x4 __attribute__((ext_vector_type(4)));

__device__ __forceinline__ short f2bf(float f) {
  union { float f; unsigned i; } v; v.f = f;
  unsigned r = (v.i + 0x7fffu + ((v.i >> 16) & 1u)) >> 16;   // RNE
  return (short)r;
}

#if defined(__has_builtin)
#if __has_builtin(__builtin_amdgcn_cvt_pk_bf16_f32)
#define HAVE_CVT_PK_BF16 1
#endif
#endif

// pack two f32 -> bf16 pair (lo=a, hi=b)
__device__ __forceinline__ unsigned PK2(float a, float b) {
#ifdef HAVE_CVT_PK_BF16
  typedef __bf16 bf16x2_t __attribute__((ext_vector_type(2)));
  union { bf16x2_t v; unsigned u; } cv;
  cv.v = __builtin_amdgcn_cvt_pk_bf16_f32(a, b);
  return cv.u;
#else
  union { float f; unsigned u; } ua, ub; ua.f = a; ub.f = b;
  unsigned ra = ua.u + 0x7fffu + ((ua.u >> 16) & 1u);
  unsigned rb = ub.u + 0x7fffu + ((ub.u >> 16) & 1u);
  return __builtin_amdgcn_perm(rb, ra, 0x07060302u);
#endif
}

// dirty-hi f32x2 unpack of a bf16 pair: elem0 exact (d<<16), elem1 keeps the
// junk low 16 mantissa bits (rel err ~2^-16, far below the 2^-9 bf16 repack
// rounding). 1 VALU op per dword; blend chains on f32x2 emit v_pk_fma_f32.
__device__ __forceinline__ f32x2 up2d(unsigned d) {
  union { unsigned u; float f; } lo, hi;
  lo.u = d << 16; hi.u = d;
  return (f32x2){lo.f, hi.f};
}

// ws layout (bytes):
//   [0,     36864)  wOf bf16 [j:9][ks:2][q:4][m:32][i:8]  (A-frag order, m>=27 zero)
//   [36864, 110592) wA  bf16 [j:9][ks:2][q:4][o:64][i:8]  (A-frag order)

__global__ __launch_bounds__(256) void wprep(const float* __restrict__ w_off,
                                             const float* __restrict__ w_conv,
                                             short* __restrict__ wOf,
                                             short* __restrict__ wA) {
  int t = blockIdx.x * 256 + threadIdx.x;
  if (t < 36864) {
    int i = t & 7, o = (t >> 3) & 63, q = (t >> 9) & 3, ks = (t >> 11) & 1, j = t >> 12;
    int c = ks * 32 + q * 8 + i;
    wA[t] = f2bf(w_conv[o * 576 + c * 9 + j]);
  }
  if (t < 18432) {
    int i = t & 7, m = (t >> 3) & 31, q = (t >> 8) & 3, ks = (t >> 10) & 1, j = t >> 11;
    int c = ks * 32 + q * 8 + i;
    wOf[t] = (m < 27) ? f2bf(w_off[(m * 64 + c) * 9 + j]) : (short)0;
  }
}

// Fully fused: stage f32 NCHW -> bf16 NHWC halo tile in SWIZZLED LDS
// (zero-filled OOB, one barrier), offset conv (MFMA), shuffle-exchange
// offsets, LDS-gather sampling + MFMA GEMM (f32 global fallback for |o|>=1).
// Round-10 = round-9 geometry + round-7 phase-3 dataflow. The r8/r9 phantom
// HBM traffic (WRITE 33->57MB) was SCRATCH: u32x4 A00..B11 declared before
// the intile/fallback branch and component-assigned in both branches get
// demoted to scratch (rule: partially-defined ext_vectors across divergent
// branches). Fix: F0u/F1u scalars are the only values crossing the branch;
// all u32x4 loads are branch-local (r7's structure, measured clean 32.8MB).
__global__ __launch_bounds__(256)
__attribute__((amdgpu_waves_per_eu(4)))
void dfuse(const float* __restrict__ x,
           const short* __restrict__ wOf,
           const float* __restrict__ b_off,
           const short* __restrict__ wA,
           float* __restrict__ out) {
  __shared__ __align__(16) unsigned lds_[TILEDW];

  int bi  = blockIdx.x & 7;        // XCD-aligned image index
  int tid = blockIdx.x >> 3;       // 0..255 tile within image
  int h0  = (tid >> 2) << 1;       // 0,2,..,126
  int w0  = (tid & 3) << 5;        // 0,32,64,96
  int t   = threadIdx.x;
  int wv  = t >> 6, l = t & 63;
  int col = l & 15, q = l >> 4;
  int px_local = wv * 16 + col;    // 0..63
  int rl  = px_local >> 5;         // local row 0..1
  int cl  = px_local & 31;         // local col 0..31
  int h   = h0 + rl;
  int w   = w0 + cl;
  int p   = h * HW_ + w;

  const float* xB = x + (size_t)bi * (CIN_ * IMG_);

  // ---- stage halo tile: rows h0-2..h0+3, cols w0-4..w0+35, 64 ch bf16 ----
  // unit u: cc = u%10 (4-px chunk), cq = (u/10)%8 (channels 8cq..8cq+7),
  // r = u/80. Unit A = t, unit B = t+256 (first 224 threads only).
  // Write: one ds_write_b128 per pixel at swizzled chunk (cq ^ (c&7)).
  {
    f32x4 L0a[4], L1a[4], L0b[4], L1b[4];
    int baseA, baseB, swA, swB;
    unsigned ma, mb;
    {
      int u = t;
      int cc = u % 10, cq = (u / 10) & 7, r = u / 80;
      int y  = h0 - 2 + r;
      int ys = min(max(y, 0), HW_ - 1);
      int xg0 = w0 - 4 + cc * 4;
      int xs  = min(max(xg0, 0), HW_ - 4);             // 16B-aligned
      ma = ((y >= 0) && (y < HW_) && (xg0 >= 0) && (xg0 < HW_)) ? 0xffffffffu : 0u;
      const float* s0 = xB + (size_t)(8 * cq) * IMG_ + ys * HW_ + xs;
#pragma unroll
      for (int i = 0; i < 4; ++i) {
        L0a[i] = *(const f32x4*)(s0 + (2 * i) * IMG_);
        L1a[i] = *(const f32x4*)(s0 + (2 * i + 1) * IMG_);
      }
      baseA = (r * TC_ + cc * 4) * PIT_;
      swA   = cq ^ ((cc & 1) << 2);          // ^ pxi applied per store
    }
    bool hasB = (t + 256) < NU_;
    {
      int u = hasB ? (t + 256) : 0;
      int cc = u % 10, cq = (u / 10) & 7, r = u / 80;
      int y  = h0 - 2 + r;
      int ys = min(max(y, 0), HW_ - 1);
      int xg0 = w0 - 4 + cc * 4;
      int xs  = min(max(xg0, 0), HW_ - 4);
      mb = ((y >= 0) && (y < HW_) && (xg0 >= 0) && (xg0 < HW_)) ? 0xffffffffu : 0u;
      const float* s0 = xB + (size_t)(8 * cq) * IMG_ + ys * HW_ + xs;
#pragma unroll
      for (int i = 0; i < 4; ++i) {
        L0b[i] = *(const f32x4*)(s0 + (2 * i) * IMG_);
        L1b[i] = *(const f32x4*)(s0 + (2 * i + 1) * IMG_);
      }
      baseB = (r * TC_ + cc * 4) * PIT_;
      swB   = cq ^ ((cc & 1) << 2);
    }
#pragma unroll
    for (int pxi = 0; pxi < 4; ++pxi) {
      u32x4 v;
#pragma unroll
      for (int i = 0; i < 4; ++i) v[i] = PK2(L0a[i][pxi], L1a[i][pxi]) & ma;
      *(u32x4*)(lds_ + baseA + pxi * PIT_ + ((swA ^ pxi) << 2)) = v;
    }
    if (hasB) {
#pragma unroll
      for (int pxi = 0; pxi < 4; ++pxi) {
        u32x4 v;
#pragma unroll
        for (int i = 0; i < 4; ++i) v[i] = PK2(L0b[i][pxi], L1b[i][pxi]) & mb;
        *(u32x4*)(lds_ + baseB + pxi * PIT_ + ((swB ^ pxi) << 2)) = v;
      }
    }
  }
  __syncthreads();

  // ---- phase 1: offset conv from tile (tile is zero-padded: no masking) ----
  float oall[32];
  {
    const short* wq_ = wOf + q * 256 + col * 8;
    f32x4 a0v = {0.f, 0.f, 0.f, 0.f};
    f32x4 a1v = {0.f, 0.f, 0.f, 0.f};
    f32x4 a0w = {0.f, 0.f, 0.f, 0.f};
    f32x4 a1w = {0.f, 0.f, 0.f, 0.f};
    const unsigned* tbp = lds_ + ((rl + 2) * TC_ + (cl + 4)) * PIT_;
#pragma unroll
    for (int j = 0; j < 9; ++j) {
      int dy = j / 3 - 1, dx = j % 3 - 1;
      int ca = (q ^ ((cl + 4 + dx) & 7)) << 2;
      const unsigned* pb = tbp + (dy * TC_ + dx) * PIT_;
      union { u32x4 u; s16x8 v; } B0, B1;
      B0.u = *(const u32x4*)(pb + ca);
      B1.u = *(const u32x4*)(pb + (ca ^ 16));
      const short* wj = wq_ + j * 2048;
      s16x8 a00 = *(const s16x8*)(wj);
      s16x8 a01 = *(const s16x8*)(wj + 128);
      s16x8 a10 = *(const s16x8*)(wj + 1024);
      s16x8 a11 = *(const s16x8*)(wj + 1024 + 128);
      a0v = __builtin_amdgcn_mfma_f32_16x16x32_bf16(a00, B0.v, a0v, 0, 0, 0);
      a1v = __builtin_amdgcn_mfma_f32_16x16x32_bf16(a01, B0.v, a1v, 0, 0, 0);
      a0w = __builtin_amdgcn_mfma_f32_16x16x32_bf16(a10, B1.v, a0w, 0, 0, 0);
      a1w = __builtin_amdgcn_mfma_f32_16x16x32_bf16(a11, B1.v, a1w, 0, 0, 0);
    }
    a0v += a0w;
    a1v += a1w;
    // bias + sigmoid by producer lanes, then wave-local shuffle exchange
    float myv[8];
#pragma unroll
    for (int r = 0; r < 4; ++r) myv[r] = a0v[r] + b_off[q * 4 + r];
#pragma unroll
    for (int r = 0; r < 4; ++r) {
      int ch = 16 + q * 4 + r;
      float bo = b_off[min(ch, 26)];
      float v = a1v[r] + bo;
      myv[4 + r] = (ch >= 18) ? (1.f / (1.f + __expf(-v))) : v;
    }
#pragma unroll
    for (int qq = 0; qq < 4; ++qq) {
      int src = qq * 16 + col;
#pragma unroll
      for (int r = 0; r < 4; ++r) {
        oall[qq * 4 + r]      = __shfl(myv[r], src);
        oall[16 + qq * 4 + r] = __shfl(myv[4 + r], src);
      }
    }
  }

  // ---- phase 3: LDS-gather sampling + MFMA GEMM ----
  f32x4 acc[4], accB[4];
#pragma unroll
  for (int ms = 0; ms < 4; ++ms) {
    acc[ms]  = (f32x4){0.f, 0.f, 0.f, 0.f};
    accB[ms] = (f32x4){0.f, 0.f, 0.f, 0.f};
  }

  const short* wqA = wA + q * 512 + col * 8;

#pragma unroll
  for (int j = 0; j < 9; ++j) {
    float o1 = oall[j], o2 = oall[9 + j], mk = oall[18 + j];

    float pxf = o1 + (float)(w + (j % 3) - 1);
    float pyf = o2 + (float)(h + (j / 3) - 1);
    float fx = floorf(pxf), fy = floorf(pyf);
    int   x0 = (int)fx,   y0 = (int)fy;
    float ax = pxf - fx, ay = pyf - fy;
    float bx = 1.f - ax, by = 1.f - ay;

    // validity factorizes per-axis: zero the axis weight instead of the product
    bx = (x0 >= 0  && x0 < HW_)     ? bx : 0.f;
    ax = (x0 >= -1 && x0 < HW_ - 1) ? ax : 0.f;
    by = (y0 >= 0  && y0 < HW_)     ? by : 0.f;
    ay = (y0 >= -1 && y0 < HW_ - 1) ? ay : 0.f;
    float bym = by * mk, aym = ay * mk;
    float u00 = bym * bx, u01 = bym * ax;
    float u10 = aym * bx, u11 = aym * ax;
    f32x2 U00 = {u00, u00}, U01 = {u01, u01};
    f32x2 U10 = {u10, u10}, U11 = {u11, u11};

    unsigned F0u[4], F1u[4];
    bool intile = (o1 >= -1.f) && (o1 < 1.f) && (o2 >= -1.f) && (o2 < 1.f);
    if (intile) {
      // r0 in [0,4], c0 in [2,36] -> no clamps; swizzled chunk addressing.
      // All u32x4 temporaries are BRANCH-LOCAL (scratch-demotion fix).
      int r0 = y0 - (h0 - 2), c0 = x0 - (w0 - 4);
      const unsigned* b00 = lds_ + (r0 * TC_ + c0) * PIT_;
      int s0 = (q ^ (c0 & 7)) << 2;
      int s1 = (q ^ ((c0 + 1) & 7)) << 2;
      u32x4 A00 = *(const u32x4*)(b00 + s0);
      u32x4 A01 = *(const u32x4*)(b00 + PIT_ + s1);
      u32x4 A10 = *(const u32x4*)(b00 + TC_ * PIT_ + s0);
      u32x4 A11 = *(const u32x4*)(b00 + TC_ * PIT_ + PIT_ + s1);
      u32x4 B00 = *(const u32x4*)(b00 + (s0 ^ 16));
      u32x4 B01 = *(const u32x4*)(b00 + PIT_ + (s1 ^ 16));
      u32x4 B10 = *(const u32x4*)(b00 + TC_ * PIT_ + (s0 ^ 16));
      u32x4 B11 = *(const u32x4*)(b00 + TC_ * PIT_ + PIT_ + (s1 ^ 16));
#pragma unroll
      for (int i = 0; i < 4; ++i) {
        f32x2 v0 = up2d(A00[i]) * U00 + up2d(A01[i]) * U01
                 + up2d(A10[i]) * U10 + up2d(A11[i]) * U11;   // v_pk_fma_f32
        F0u[i] = PK2(v0.x, v0.y);
        f32x2 v1 = up2d(B00[i]) * U00 + up2d(B01[i]) * U01
                 + up2d(B10[i]) * U10 + up2d(B11[i]) * U11;
        F1u[i] = PK2(v1.x, v1.y);
      }
    } else {
      // rare fallback: gather straight from f32 NCHW x (clamps only here)
      int xc0 = min(max(x0, 0), HW_ - 1), xc1 = min(max(x0 + 1, 0), HW_ - 1);
      int yc0 = min(max(y0, 0), HW_ - 1), yc1 = min(max(y0 + 1, 0), HW_ - 1);
      int g00 = yc0 * HW_ + xc0, g01 = yc0 * HW_ + xc1;
      int g10 = yc1 * HW_ + xc0, g11 = yc1 * HW_ + xc1;
      for (int hB = 0; hB < 2; ++hB) {
        for (int ii = 0; ii < 4; ++ii) {
          int c0i = hB * 32 + q * 8 + 2 * ii;
          const float* pc = xB + c0i * IMG_;
          const float* pd = pc + IMG_;
          float va = u00 * pc[g00] + u01 * pc[g01] + u10 * pc[g10] + u11 * pc[g11];
          float vb = u00 * pd[g00] + u01 * pd[g01] + u10 * pd[g10] + u11 * pd[g11];
          if (hB) F1u[ii] = PK2(va, vb); else F0u[ii] = PK2(va, vb);
        }
      }
    }

    union { unsigned u[4]; s16x8 v; } F0, F1;
#pragma unroll
    for (int i = 0; i < 4; ++i) { F0.u[i] = F0u[i]; F1.u[i] = F1u[i]; }

    const short* wj = wqA + j * 4096;
#pragma unroll
    for (int ms = 0; ms < 4; ++ms) {
      s16x8 a0 = *(const s16x8*)(wj + ms * 128);
      acc[ms] = __builtin_amdgcn_mfma_f32_16x16x32_bf16(a0, F0.v, acc[ms], 0, 0, 0);
    }
#pragma unroll
    for (int ms = 0; ms < 4; ++ms) {
      s16x8 a1 = *(const s16x8*)(wj + 2048 + ms * 128);
      accB[ms] = __builtin_amdgcn_mfma_f32_16x16x32_bf16(a1, F1.v, accB[ms], 0, 0, 0);
    }
  }

  float* op = out + (size_t)bi * (CIN_ * IMG_) + p;
#pragma unroll
  for (int ms = 0; ms < 4; ++ms) {
    f32x4 r = acc[ms] + accB[ms];
#pragma unroll
    for (int rr = 0; rr < 4; ++rr)
      op[(ms * 16 + q * 4 + rr) * IMG_] = r[rr];
  }
}

extern "C" void kernel_launch(void* const* d_in, const int* in_sizes, int n_in,
                              void* d_out, int out_size, void* d_ws, size_t ws_size,
                              hipStream_t stream) {
  const float* x      = (const float*)d_in[0];
  const float* w_off  = (const float*)d_in[1];
  const float* b_off  = (const float*)d_in[2];
  const float* w_conv = (const float*)d_in[3];
  float* out = (float*)d_out;

  char* ws = (char*)d_ws;
  short* wOf = (short*)(ws);
  short* wA  = (short*)(ws + 36864);

  hipLaunchKernelGGL(wprep, dim3(144),  dim3(256), 0, stream, w_off, w_conv, wOf, wA);
  hipLaunchKernelGGL(dfuse, dim3(2048), dim3(256), 0, stream, x, wOf, b_off, wA, out);
}